// Round 5
// baseline (238.216 us; speedup 1.0000x reference)
//
#include <hip/hip_runtime.h>
#include <hip/hip_bf16.h>

// 2-layer GCN + mean pool. N=100000, E=1600000, G=128. dims 3 -> 64 -> 128.
//   h1  = relu( (A_hat x) @ W1 + b1 )
//   out = (mean_g (A_hat h1)) @ W2 + b2
//
// R14 -> R15 (preprocessing diet; gather2 frozen):
//   R14 post-mortem: gather2 46.5us is only 20% of the 234us total; the
//   other 7 kernels + gaps are ~188us. Changes:
//   * k_detect: 1-thread serial 192-load chain -> 64-lane ballot probe.
//   * CSR (meta/row_ptr) ELIMINATED. k_sort rewritten: no 256-scan, no
//     SCAP stage, no ballot partition, no meta write. Direct LDS-cursor
//     partition into meta2 keyed by (srange, grel) where grel =
//     min(g - g_base(bucket), 3): per-segment g stays monotone without
//     stable ordering (a 256-node bucket spans <=2-3 graphs).
//   * k_l1: LDS fp32-atomic aggregation straight from edges2 (self term
//     = register init with xs[node]); applies dinv_dst post-aggregation.
//   * k_bscan: bktoff scan dropped (only bktoff2/gcur/m2off/sQ remain).
//   k_count, k_split, k_gather2, k_out unchanged from R14.
//
// DTYPE-ADAPTIVE: k_detect probes raw bits: flags[0]=bf16?, flags[1]=int64?

typedef __hip_bfloat16 bf16;
#define NGRAPH 128
#define NSLICE 8
#define TILE_C 8192
#define TILE_S 4096

__device__ __forceinline__ float b2f(bf16 v) { return __bfloat162float(v); }
__device__ __forceinline__ float bfb(unsigned short u) {
    return __uint_as_float((unsigned)u << 16);
}
__device__ __forceinline__ float fld(const void* p, long long i, int isbf) {
    return isbf ? b2f(((const bf16*)p)[i]) : ((const float*)p)[i];
}
__device__ __forceinline__ int ild(const void* p, long long i, int is64) {
    return is64 ? (int)((const long long*)p)[i] : ((const int*)p)[i];
}
// src-range: 8 ranges of ~12788 nodes; s = (src*41)>>19 (src<2^17 so no ovf)
__device__ __forceinline__ int srange(unsigned src) {
    return (int)((src * 41u) >> 19);
}

// ---- dtype probe (64-lane parallel) -------------------------------------
__global__ void k_detect(const void* x, const void* ei, int* flags) {
    int lane = threadIdx.x & 63;
    const unsigned short* u = (const unsigned short*)x;
    int e0 = (u[2 * lane] >> 7) & 0xFF;
    int e1 = (u[2 * (lane + 64)] >> 7) & 0xFF;
    unsigned long long ba = __ballot(e0 >= 90 && e0 <= 135);
    unsigned long long bb = __ballot(e1 >= 90 && e1 <= 135);
    int good = __popcll(ba) + __popcll(bb);
    const int* w = (const int*)ei;
    unsigned long long bz = __ballot(w[2 * lane + 1] == 0);
    int zeros = __popcll(bz);
    if (lane == 0 && blockIdx.x == 0) {
        flags[0] = (good >= 96) ? 1 : 0;          // bf16 mode
        flags[1] = (zeros >= 56) ? 1 : 0;         // int64 mode
    }
}

// ---- bucket histogram of dst>>8, plus (srange, bucket) matrix -----------
__global__ void k_count(const void* __restrict__ ei, int* __restrict__ cnt,
                        int* __restrict__ cnt2, int E, int NB,
                        const int* __restrict__ flags) {
    __shared__ int h[512];
    __shared__ int h2[4096];
    for (int e = threadIdx.x; e < 512; e += 256) h[e] = 0;
    for (int e = threadIdx.x; e < 4096; e += 256) h2[e] = 0;
    __syncthreads();
    int is64 = flags[1];
    long long base = (long long)blockIdx.x * TILE_C;
    int lim = (int)min((long long)TILE_C, (long long)E - base);
    for (int k = threadIdx.x; k < lim; k += 256) {
        int d = ild(ei, (long long)E + base + k, is64);
        int s = ild(ei, base + k, is64);
        int sr = srange((unsigned)s);
        atomicAdd(&h[d >> 8], 1);
        atomicAdd(&h2[(sr << 9) | (d >> 8)], 1);
    }
    __syncthreads();
    for (int e = threadIdx.x; e < NB; e += 256)
        if (h[e]) atomicAdd(&cnt[e], h[e]);
    for (int e = threadIdx.x; e < 4096; e += 256)
        if (h2[e]) atomicAdd(&cnt2[e], h2[e]);
}

// ---- bucket offsets + meta2 segment offsets (1 block, 512 thr) ----------
// bktoff2 = excl scan of cnt; gcur = copy. m2off[s*512+b] = excl scan of
// (cnt2 + analytic self-loop counts) over (s,b); sQ[s] = stream base.
__global__ void k_bscan(const int* __restrict__ cnt, const int* __restrict__ cnt2,
                        int* __restrict__ bktoff2, int* __restrict__ gcur,
                        int* __restrict__ m2off, int* __restrict__ sQ,
                        int N, int NB, int Etot) {
    __shared__ int sa[512];
    int i = threadIdx.x;
    int va = (i < NB) ? cnt[i] : 0;
    sa[i] = va;
    __syncthreads();
    for (int d = 1; d < 512; d <<= 1) {
        int ta = (i >= d) ? sa[i - d] : 0;
        __syncthreads();
        sa[i] += ta;
        __syncthreads();
    }
    if (i < NB) { bktoff2[i] = sa[i] - va; gcur[i] = sa[i] - va; }
    if (i == NB - 1) bktoff2[NB] = sa[i];
    __syncthreads();
    // phase 2: 8 entries per thread over padded [8][512]
    int lo8[8]; int tsum = 0;
#pragma unroll
    for (int k = 0; k < 8; ++k) {
        int e = (i << 3) + k;
        int s = e >> 9, bb = e & 511;
        int v = 0;
        if (bb < NB) {
            v = cnt2[e];
            // self-loop records: nodes in bucket bb whose srange == s
            int node0 = bb << 8;
            int nl = min(256, N - node0);
            int slo = (s * 524288 + 40) / 41;
            int shi = ((s + 1) * 524288 + 40) / 41;
            int lo = max(node0, slo), hi = min(node0 + nl, shi);
            if (hi > lo) v += hi - lo;
        }
        lo8[k] = tsum; tsum += v;
    }
    sa[i] = tsum;
    __syncthreads();
    for (int d = 1; d < 512; d <<= 1) {
        int t = (i >= d) ? sa[i - d] : 0;
        __syncthreads();
        sa[i] += t;
        __syncthreads();
    }
    int basee = sa[i] - tsum;
#pragma unroll
    for (int k = 0; k < 8; ++k) m2off[(i << 3) + k] = basee + lo8[k];
    __syncthreads();
    if (i < 8) sQ[i] = m2off[i << 9];
    if (i == 8) sQ[8] = Etot;
}

// ---- multisplit by dst bucket (edges2 packed: src | dloc<<24) -----------
__global__ void k_split(const void* __restrict__ ei, unsigned* __restrict__ edges2,
                        int* __restrict__ gcur, int E, int NB,
                        const int* __restrict__ flags) {
    __shared__ int hist[512], scan_[512], gbase[512], lcur[512];
    __shared__ int2 stage[TILE_S];
    int is64 = flags[1];
    long long base = (long long)blockIdx.x * TILE_S;
    int lim = (int)min((long long)TILE_S, (long long)E - base);
    for (int b = threadIdx.x; b < 512; b += 256) hist[b] = 0;
    __syncthreads();
    for (int k = threadIdx.x; k < lim; k += 256) {
        int d = ild(ei, (long long)E + base + k, is64);
        atomicAdd(&hist[d >> 8], 1);
    }
    __syncthreads();
    // parallel exclusive scan of hist (512 entries, 256 threads)
    {
        int i0 = threadIdx.x, i1 = threadIdx.x + 256;
        scan_[i0] = hist[i0]; scan_[i1] = hist[i1];
        __syncthreads();
        for (int d = 1; d < 512; d <<= 1) {
            int t0 = (i0 >= d) ? scan_[i0 - d] : 0;
            int t1 = (i1 >= d) ? scan_[i1 - d] : 0;
            __syncthreads();
            scan_[i0] += t0; scan_[i1] += t1;
            __syncthreads();
        }
        int e0 = scan_[i0] - hist[i0];
        int e1 = scan_[i1] - hist[i1];
        __syncthreads();
        scan_[i0] = e0; scan_[i1] = e1;
        __syncthreads();
    }
    for (int b = threadIdx.x; b < NB; b += 256) {
        lcur[b] = scan_[b];
        gbase[b] = hist[b] ? atomicAdd(&gcur[b], hist[b]) : 0;
    }
    __syncthreads();
    for (int k = threadIdx.x; k < lim; k += 256) {
        int s = ild(ei, base + k, is64);
        int d = ild(ei, (long long)E + base + k, is64);
        int p = atomicAdd(&lcur[d >> 8], 1);
        stage[p] = make_int2(d, s);
    }
    __syncthreads();
    for (int t = threadIdx.x; t < lim; t += 256) {
        int2 r = stage[t];
        int b = r.x >> 8;
        edges2[gbase[b] + (t - scan_[b])] =
            (unsigned)r.y | ((unsigned)(r.x & 255) << 24);
    }
}

// ---- per-bucket node pass + direct meta2 partition ----------------------
// meta2 record = src | g(dst)<<17 | min(deg(dst),255)<<24. Partition key
// (srange(src), grel) with grel = min(g - g_base, 3): segment order is
// g-monotone; stability not needed. Also writes dinv/xs/start.
__global__ void k_sort(const unsigned* __restrict__ edges2, const void* __restrict__ batch,
                       const void* __restrict__ x, const int* __restrict__ cnt,
                       const int* __restrict__ bktoff2, const int* __restrict__ m2off,
                       unsigned* __restrict__ meta2,
                       float* __restrict__ dinv, float4* __restrict__ xs,
                       int* __restrict__ start, int N,
                       const int* __restrict__ flags) {
    __shared__ int hist[256];
    __shared__ int grl[256];
    __shared__ unsigned gdeg[256];
    __shared__ int h32[32], cur32[32];
    int b = blockIdx.x;
    int node0 = b << 8;
    int nloc = min(256, N - node0);
    int is64 = flags[1], isbf = flags[0];
    int i = threadIdx.x;
    hist[i] = 0;
    if (i < 32) h32[i] = 0;
    int gbase = ild(batch, node0, is64);   // broadcast load
    int g_i = 0;
    if (i < nloc) {
        int node = node0 + i;
        g_i = ild(batch, node, is64);
        grl[i] = min(g_i - gbase, 3);
        // graph boundary detection (batch sorted)
        int gp = (node == 0) ? -1 : ild(batch, node - 1, is64);
        for (int q = gp + 1; q <= g_i; ++q) start[q] = node;
        if (node == N - 1)
            for (int q = g_i + 1; q <= NGRAPH; ++q) start[q] = N;
    }
    __syncthreads();
    int rbase = bktoff2[b], rcnt = cnt[b];
    // pass 1: deg histogram + (s,grel) counts (edges + self)
    if (i < nloc)
        atomicAdd(&h32[(srange((unsigned)(node0 + i)) << 2) | grl[i]], 1);
    for (int t = i; t < rcnt; t += 256) {
        unsigned r = edges2[rbase + t];
        int dl = (int)(r >> 24);
        atomicAdd(&hist[dl], 1);
        atomicAdd(&h32[(srange(r & 0xFFFFFFu) << 2) | grl[dl]], 1);
    }
    __syncthreads();
    // cursors: per-s exclusive prefix over grel (thread 0, 32 ops)
    if (i == 0) {
        for (int s = 0; s < 8; ++s) {
            int sb = m2off[(s << 9) | b];
            int run = 0;
            for (int r = 0; r < 4; ++r) {
                cur32[(s << 2) | r] = sb + run;
                run += h32[(s << 2) | r];
            }
        }
    }
    // per-node outputs (deg now ready)
    if (i < nloc) {
        int node = node0 + i;
        int dg = hist[i];
        float di = rsqrtf((float)(dg + 1));
        dinv[node] = di;
        xs[node] = make_float4(di * fld(x, 3LL * node, isbf),
                               di * fld(x, 3LL * node + 1, isbf),
                               di * fld(x, 3LL * node + 2, isbf), 0.0f);
        gdeg[i] = ((unsigned)g_i << 17) | ((unsigned)min(dg, 255) << 24);
    }
    __syncthreads();
    // pass 2: emit meta2 (self + edges)
    if (i < nloc) {
        unsigned node = (unsigned)(node0 + i);
        int p = atomicAdd(&cur32[(srange(node) << 2) | grl[i]], 1);
        meta2[p] = node | gdeg[i];
    }
    for (int t = i; t < rcnt; t += 256) {
        unsigned r = edges2[rbase + t];
        int dl = (int)(r >> 24);
        unsigned src = r & 0xFFFFFFu;
        int p = atomicAdd(&cur32[(srange(src) << 2) | grl[dl]], 1);
        meta2[p] = src | gdeg[dl];
    }
}

// ---- layer 1: LDS-atomic aggregation from edges2 + tiny GEMM + relu -----
__global__ void k_l1(const float4* __restrict__ xs, const float* __restrict__ dinv,
                     const unsigned* __restrict__ edges2, const int* __restrict__ bktoff2,
                     const int* __restrict__ cnt,
                     const void* __restrict__ W1, const void* __restrict__ b1,
                     bf16* __restrict__ hs1, int N, const int* __restrict__ flags) {
    __shared__ float w[256];        // [0..191]=W1 (3x64 row-major), [192..255]=b1
    __shared__ float ag[256][4];
    int isbf = flags[0];
    if (threadIdx.x < 192) w[threadIdx.x] = fld(W1, threadIdx.x, isbf);
    if (threadIdx.x < 64) w[192 + threadIdx.x] = fld(b1, threadIdx.x, isbf);
    int b = blockIdx.x;
    int node0 = b << 8;
    int nloc = min(256, N - node0);
    int i = threadIdx.x;
    float di = 0.f;
    if (i < nloc) {
        int node = node0 + i;
        float4 sv = xs[node];         // self term (already dinv_src-scaled)
        di = dinv[node];
        ag[i][0] = sv.x; ag[i][1] = sv.y; ag[i][2] = sv.z; ag[i][3] = di;
    }
    __syncthreads();
    int rbase = bktoff2[b], rcnt = cnt[b];
    for (int t = i; t < rcnt; t += 256) {
        unsigned r = edges2[rbase + t];
        int dl = (int)(r >> 24);
        float4 vv = xs[r & 0xFFFFFFu];
        atomicAdd(&ag[dl][0], vv.x);
        atomicAdd(&ag[dl][1], vv.y);
        atomicAdd(&ag[dl][2], vv.z);
    }
    __syncthreads();
    if (i < nloc) { ag[i][0] *= di; ag[i][1] *= di; ag[i][2] *= di; }
    __syncthreads();
    for (int t = threadIdx.x; t < (nloc << 6); t += 256) {
        int ii = t >> 6, j = t & 63;
        float acc = ag[ii][0] * w[j] + ag[ii][1] * w[64 + j] + ag[ii][2] * w[128 + j]
                  + w[192 + j];
        hs1[(size_t)(node0 + ii) * 64 + j] = __float2bfloat16(ag[ii][3] * fmaxf(acc, 0.0f));
    }
}

// ---- layer 2 + pool: src-range streams, XCD-pinned (UNCHANGED R14) ------
__global__ void k_gather2(const uint4* __restrict__ hs1q, const unsigned* __restrict__ meta2,
                          const int* __restrict__ sQ, float* __restrict__ P) {
    int sidx = blockIdx.x & 7;
    int bsub = blockIdx.x >> 3;
    int warp = threadIdx.x >> 6;
    int lane = threadIdx.x & 63;
    int q = lane >> 3;          // group 0..7
    int l8 = lane & 7;          // lane in group -> features [8*l8, 8*l8+8)
    int s0 = sQ[sidx], s1 = sQ[sidx + 1];
    int len = s1 - s0;
    int wv = (bsub << 2) | warp;               // 0..1023 within stream
    int chunk = (len + 1023) >> 10;
    long long base = (long long)s0 + (long long)wv * chunk;
    if (base >= (long long)s1) return;
    long long end = base + chunk;
    if (end > (long long)s1) end = (long long)s1;
    float acc[8] = {0.f, 0.f, 0.f, 0.f, 0.f, 0.f, 0.f, 0.f};
    int gcur = -1;
#define GFLUSH()                                                                \
    if (gcur >= 0) {                                                            \
        float* dp = P + (size_t)q * (NGRAPH * 64) + (size_t)gcur * 64 + (l8 << 3); \
        _Pragma("unroll")                                                       \
        for (int k = 0; k < 8; ++k) { atomicAdd(dp + k, acc[k]); acc[k] = 0.f; }\
    }
#define STEP(m, v)                                                              \
    {                                                                           \
        int g = (int)((m >> 17) & 0x7Fu);                                       \
        float w = rsqrtf((float)((m >> 24) & 0xFFu) + 1.0f);                    \
        if (g != gcur) { GFLUSH(); gcur = g; }                                  \
        acc[0] += w * __uint_as_float(v.x << 16);                               \
        acc[1] += w * __uint_as_float(v.x & 0xFFFF0000u);                       \
        acc[2] += w * __uint_as_float(v.y << 16);                               \
        acc[3] += w * __uint_as_float(v.y & 0xFFFF0000u);                       \
        acc[4] += w * __uint_as_float(v.z << 16);                               \
        acc[5] += w * __uint_as_float(v.z & 0xFFFF0000u);                       \
        acc[6] += w * __uint_as_float(v.w << 16);                               \
        acc[7] += w * __uint_as_float(v.w & 0xFFFF0000u);                       \
    }
    long long p = base + q;
    for (; p + 24 < end; p += 32) {
        unsigned m0 = meta2[p];
        unsigned m1 = meta2[p + 8];
        unsigned m2 = meta2[p + 16];
        unsigned m3 = meta2[p + 24];
        uint4 v0 = hs1q[(size_t)(m0 & 0x1FFFFu) * 8 + l8];
        uint4 v1 = hs1q[(size_t)(m1 & 0x1FFFFu) * 8 + l8];
        uint4 v2 = hs1q[(size_t)(m2 & 0x1FFFFu) * 8 + l8];
        uint4 v3 = hs1q[(size_t)(m3 & 0x1FFFFu) * 8 + l8];
        STEP(m0, v0) STEP(m1, v1) STEP(m2, v2) STEP(m3, v3)
    }
    for (; p < end; p += 8) {
        unsigned m = meta2[p];
        uint4 v = hs1q[(size_t)(m & 0x1FFFFu) * 8 + l8];
        STEP(m, v)
    }
    // final flush
    {
        int g0 = __shfl(gcur, 0);
        if (g0 >= 0 && __all(gcur == g0)) {
#pragma unroll
            for (int k = 0; k < 8; ++k) {
                acc[k] += __shfl_xor(acc[k], 8);
                acc[k] += __shfl_xor(acc[k], 16);
                acc[k] += __shfl_xor(acc[k], 32);
            }
            if (q == 0) {
                float* dp = P + (size_t)(wv & (NSLICE - 1)) * (NGRAPH * 64)
                              + (size_t)g0 * 64 + (l8 << 3);
#pragma unroll
                for (int k = 0; k < 8; ++k) atomicAdd(dp + k, acc[k]);
            }
        } else {
            GFLUSH();
        }
    }
#undef STEP
#undef GFLUSH
}

// out[g][j] = (sum_slices P[g]/count_g) . W2[:,j] + b2[j]  (0 if empty graph)
__global__ void k_out(const float* __restrict__ P, const int* __restrict__ start,
                      const void* __restrict__ W2, const void* __restrict__ b2v,
                      void* __restrict__ out, const int* __restrict__ flags) {
    __shared__ float pm[64];
    int g = blockIdx.x, j = threadIdx.x;
    int isbf = flags[0];
    int c = start[g + 1] - start[g];
    if (j < 64) {
        float v = 0.f;
        for (int s = 0; s < NSLICE; ++s) v += P[(size_t)s * NGRAPH * 64 + g * 64 + j];
        pm[j] = (c > 0) ? v / (float)c : 0.0f;
    }
    __syncthreads();
    float acc = 0.0f;
    if (c > 0) {
        acc = fld(b2v, j, isbf);
        for (int k = 0; k < 64; ++k) acc += pm[k] * fld(W2, k * 128 + j, isbf);
    }
    if (isbf) ((bf16*)out)[g * 128 + j] = __float2bfloat16(acc);
    else      ((float*)out)[g * 128 + j] = acc;
}

extern "C" void kernel_launch(void* const* d_in, const int* in_sizes, int n_in,
                              void* d_out, int out_size, void* d_ws, size_t ws_size,
                              hipStream_t stream) {
    const void* x    = d_in[0];
    const void* ei   = d_in[1];   // edge_index [2,E] flat: src row then dst row
    const void* batch= d_in[2];
    const void* W1   = d_in[3];
    const void* b1   = d_in[4];
    const void* W2   = d_in[5];
    const void* b2   = d_in[6];

    const int N = in_sizes[0] / 3;
    const int E = in_sizes[1] / 2;
    const int Etot = E + N;
    const int NB = (N + 255) / 256;          // dst buckets (391)

    // ---- workspace layout (512B aligned), total ~31 MB ----
    char* ws = (char*)d_ws;
    size_t off = 0;
    auto alloc = [&](size_t bytes) {
        size_t o = off;
        off = (off + bytes + 511) & ~(size_t)511;
        return o;
    };
    int* flags    = (int*)(ws + alloc(64 * 4));
    int* cnt      = (int*)(ws + alloc((size_t)NB * 4));
    int* cnt2     = (int*)(ws + alloc((size_t)4096 * 4));
    int* bktoff2  = (int*)(ws + alloc((size_t)(NB + 1) * 4));
    int* gcur     = (int*)(ws + alloc((size_t)NB * 4));
    int* m2off    = (int*)(ws + alloc((size_t)4096 * 4));
    int* sQ       = (int*)(ws + alloc((size_t)16 * 4));
    int* start    = (int*)(ws + alloc((size_t)(NGRAPH + 1) * 4));
    float* dinv   = (float*)(ws + alloc((size_t)N * 4));
    unsigned* edges2 = (unsigned*)(ws + alloc((size_t)E * 4));
    unsigned* meta2  = (unsigned*)(ws + alloc((size_t)Etot * 4));
    float4* xs    = (float4*)(ws + alloc((size_t)N * 16));
    bf16* hs1     = (bf16*)(ws + alloc((size_t)N * 64 * 2));
    float* P      = (float*)(ws + alloc((size_t)NSLICE * NGRAPH * 64 * 4));
    (void)ws_size;

    (void)hipMemsetAsync(cnt, 0, (size_t)NB * 4, stream);
    (void)hipMemsetAsync(cnt2, 0, (size_t)4096 * 4, stream);
    (void)hipMemsetAsync(P, 0, (size_t)NSLICE * NGRAPH * 64 * 4, stream);

    const int cb = (E + TILE_C - 1) / TILE_C;       // 196
    const int sb = (E + TILE_S - 1) / TILE_S;       // 391

    const int g2blocks = 2048;                       // multiple of 8

    k_detect<<<1, 64, 0, stream>>>(x, ei, flags);
    k_count<<<cb, 256, 0, stream>>>(ei, cnt, cnt2, E, NB, flags);
    k_bscan<<<1, 512, 0, stream>>>(cnt, cnt2, bktoff2, gcur, m2off, sQ, N, NB, Etot);
    k_split<<<sb, 256, 0, stream>>>(ei, edges2, gcur, E, NB, flags);
    k_sort<<<NB, 256, 0, stream>>>(edges2, batch, x, cnt, bktoff2, m2off, meta2,
                                   dinv, xs, start, N, flags);
    k_l1<<<NB, 256, 0, stream>>>(xs, dinv, edges2, bktoff2, cnt, W1, b1, hs1, N, flags);
    k_gather2<<<g2blocks, 256, 0, stream>>>((const uint4*)hs1, meta2, sQ, P);
    k_out<<<NGRAPH, 128, 0, stream>>>(P, start, W2, b2, d_out, flags);
}